// Round 4
// baseline (275.977 us; speedup 1.0000x reference)
//
#include <hip/hip_runtime.h>
#include <stdint.h>

#define B_ 8
#define S_ 1024
#define H_ 768
#define NH_ 12
#define HD_ 64
#define M_ (B_*S_)   // 8192 tokens

typedef __attribute__((ext_vector_type(8))) short short8;
typedef __attribute__((ext_vector_type(4))) float floatx4;

#define MFMA16(a,b,c) __builtin_amdgcn_mfma_f32_16x16x32_bf16((a),(b),(c),0,0,0)

__device__ __forceinline__ ushort f2bf(float x){
    union { float f; unsigned u; } v; v.f = x;
    unsigned r = (v.u + 0x7fffu + ((v.u >> 16) & 1u)) >> 16;
    return (ushort)r;
}
__device__ __forceinline__ float bf2f(ushort u){
    return __uint_as_float(((unsigned)u) << 16);
}

__device__ __forceinline__ void async16(const ushort* g, ushort* l){
    __builtin_amdgcn_global_load_lds(
        (const __attribute__((address_space(1))) unsigned int*)g,
        (__attribute__((address_space(3))) unsigned int*)l, 16, 0, 0);
}

// ---------------- fused f32 -> bf16 cast for all 6 tensors ----------------
__global__ __launch_bounds__(256, 8) void cvt_all(
    const float* __restrict__ hs, const float* __restrict__ ce,
    const float* __restrict__ wq, const float* __restrict__ wk,
    const float* __restrict__ wv, const float* __restrict__ wo,
    ushort* __restrict__ hsb, ushort* __restrict__ ceb,
    ushort* __restrict__ wqb, ushort* __restrict__ wkb,
    ushort* __restrict__ wvb, ushort* __restrict__ wob)
{
    const int NA = M_*H_/4;
    const int NW = H_*H_/4;
    int i = blockIdx.x*256 + threadIdx.x;
    if (i >= 2*NA + 4*NW) return;
    const float* s; ushort* d; int off;
    if (i < NA)            { s = hs; d = hsb; off = i; }
    else if (i < 2*NA)     { s = ce; d = ceb; off = i - NA; }
    else {
        int j = i - 2*NA;
        int wsel = j / NW;
        off = j - wsel*NW;
        s = (wsel==0) ? wq : (wsel==1) ? wk : (wsel==2) ? wv : wo;
        d = (wsel==0) ? wqb : (wsel==1) ? wkb : (wsel==2) ? wvb : wob;
    }
    float4 f = ((const float4*)s)[off];
    ushort4 u;
    u.x = f2bf(f.x); u.y = f2bf(f.y); u.z = f2bf(f.z); u.w = f2bf(f.w);
    ((ushort4*)d)[off] = u;
}

// ---------------- shared GEMM body: C[M,N] = A[M,K] @ B[N,K]^T + bias ------
// BK=64, XOR-swizzled 128B-pitch LDS rows.
// MODE 0: swapped-operand MFMA (D[n][m]); bf16 out [M,768] via LDS-assembled
//         coalesced b128 stores.
// MODE 1: Vt[(b*12+h)*64+d][1024] via LDS-assembled coalesced stores.
template<int MODE>
__device__ __forceinline__ void gemm_body(
    const ushort* __restrict__ A, const ushort* __restrict__ Bw,
    const float* __restrict__ bias, ushort* __restrict__ obf,
    ushort* smem, int bx, int by)
{
    ushort* lA = smem;
    ushort* lB = smem + 8192;
    const int K = H_;
    int tid  = threadIdx.x;
    int lane = tid & 63, wave = tid >> 6;
    int m0 = bx * 128, n0 = by * 128;
    int wm = (wave >> 1) * 64, wn = (wave & 1) * 64;
    int fr = lane & 15, quad = lane >> 4, quad4 = quad*4;

    floatx4 acc[4][4];
    #pragma unroll
    for (int mt=0;mt<4;mt++)
        #pragma unroll
        for (int nt=0;nt<4;nt++)
            acc[mt][nt] = (floatx4){0.f,0.f,0.f,0.f};

    int row0 = tid >> 3;
    int csw  = ((tid & 7) ^ (row0 & 7)) * 8;
    const ushort* Ap[4]; const ushort* Bp[4];
    ushort* ldA_[4]; ushort* ldB_[4];
    #pragma unroll
    for (int j=0;j<4;j++){
        int row = row0 + 32*j;
        Ap[j] = A  + (size_t)(m0 + row) * K + csw;
        Bp[j] = Bw + (size_t)(n0 + row) * K + csw;
        ldA_[j] = lA + (tid + 256*j)*8;
        ldB_[j] = lB + (tid + 256*j)*8;
    }

    for (int k0 = 0; k0 < K; k0 += 64){
        #pragma unroll
        for (int j=0;j<4;j++) async16(Ap[j] + k0, ldA_[j]);
        #pragma unroll
        for (int j=0;j<4;j++) async16(Bp[j] + k0, ldB_[j]);
        __syncthreads();
        #pragma unroll
        for (int kk=0; kk<2; kk++){
            short8 af[4], bfr[4];
            #pragma unroll
            for (int t=0;t<4;t++){
                int ra = wm + t*16 + fr;
                int rb = wn + t*16 + fr;
                af[t]  = *(const short8*)&lA[ra*64 + (((kk*4+quad) ^ (ra&7))<<3)];
                bfr[t] = *(const short8*)&lB[rb*64 + (((kk*4+quad) ^ (rb&7))<<3)];
            }
            if (MODE == 0){
                // swapped: D[n][m] — lane holds 4 consecutive n for one token m
                #pragma unroll
                for (int mt=0;mt<4;mt++)
                    #pragma unroll
                    for (int nt=0;nt<4;nt++)
                        acc[mt][nt] = MFMA16(bfr[nt], af[mt], acc[mt][nt]);
            } else {
                #pragma unroll
                for (int mt=0;mt<4;mt++)
                    #pragma unroll
                    for (int nt=0;nt<4;nt++)
                        acc[mt][nt] = MFMA16(af[mt], bfr[nt], acc[mt][nt]);
            }
        }
        __syncthreads();
    }

    if (MODE == 0){
        // bias along n, vectorized: lane's 4 accs are consecutive n
        float4 bias4[4];
        #pragma unroll
        for (int nt=0;nt<4;nt++)
            bias4[nt] = *(const float4*)&bias[n0 + wn + nt*16 + quad4];
        // assemble [m][n] tile, pitch 132
        #pragma unroll
        for (int mt=0;mt<4;mt++){
            int m = wm + mt*16 + fr;
            #pragma unroll
            for (int nt=0;nt<4;nt++){
                ushort4 u;
                u.x = f2bf(acc[mt][nt][0] + bias4[nt].x);
                u.y = f2bf(acc[mt][nt][1] + bias4[nt].y);
                u.z = f2bf(acc[mt][nt][2] + bias4[nt].z);
                u.w = f2bf(acc[mt][nt][3] + bias4[nt].w);
                *(ushort4*)&smem[m*132 + wn + nt*16 + quad4] = u;
            }
        }
        __syncthreads();
        #pragma unroll
        for (int jj=0;jj<8;jj++){
            int idx = tid + 256*jj;          // 0..2047
            int m = idx >> 4, c = (idx & 15) * 8;
            short8 v = *(const short8*)&smem[m*132 + c];
            *(short8*)&obf[(size_t)(m0 + m)*H_ + n0 + c] = v;
        }
    } else {
        float bv_[4];
        #pragma unroll
        for (int nt=0;nt<4;nt++) bv_[nt] = bias[n0 + wn + nt*16 + fr];
        // Vt: assemble per head-half [64 d][pitch 136 q], store coalesced
        int bb = m0 >> 10, q0 = m0 & 1023;
        #pragma unroll
        for (int nh=0; nh<2; nh++){
            __syncthreads();
            if ((wave & 1) == nh){
                #pragma unroll
                for (int mt=0;mt<4;mt++){
                    int ql = wm + mt*16 + quad4;
                    #pragma unroll
                    for (int nt=0;nt<4;nt++){
                        int dl = nt*16 + fr;
                        ushort4 u;
                        u.x = f2bf(acc[mt][nt][0] + bv_[nt]);
                        u.y = f2bf(acc[mt][nt][1] + bv_[nt]);
                        u.z = f2bf(acc[mt][nt][2] + bv_[nt]);
                        u.w = f2bf(acc[mt][nt][3] + bv_[nt]);
                        *(ushort4*)&smem[dl*136 + ql] = u;
                    }
                }
            }
            __syncthreads();
            int head = by*2 + nh;
            #pragma unroll
            for (int jj=0;jj<4;jj++){
                int mI = tid + 256*jj;
                int d  = mI >> 4;
                int qc = (mI & 15) * 8;
                short8 v = *(const short8*)&smem[d*136 + qc];
                *(short8*)&obf[((size_t)((bb*NH_ + head)*HD_ + d))*S_ + q0 + qc] = v;
            }
        }
    }
}

// fused Q/K/V projection: grid (64, 6, 3)
__global__ __launch_bounds__(256, 4) void gemm_qkv(
    const ushort* __restrict__ hsb, const ushort* __restrict__ ceb,
    const ushort* __restrict__ wqb, const ushort* __restrict__ wkb,
    const ushort* __restrict__ wvb,
    const float* __restrict__ bq, const float* __restrict__ bk,
    const float* __restrict__ bv,
    ushort* __restrict__ Qb, ushort* __restrict__ Kb, ushort* __restrict__ Vtb)
{
    __shared__ ushort smem[16896];
    int z = blockIdx.z;
    if (z == 2)
        gemm_body<1>(ceb, wvb, bv, Vtb, smem, blockIdx.x, blockIdx.y);
    else
        gemm_body<0>(z ? ceb : hsb, z ? wkb : wqb, z ? bk : bq,
                     z ? Kb : Qb, smem, blockIdx.x, blockIdx.y);
}

// O-projection (bf16 out): grid (64, 6)
__global__ __launch_bounds__(256, 4) void gemm_o(
    const ushort* __restrict__ ctxb, const ushort* __restrict__ wob,
    const float* __restrict__ bo, ushort* __restrict__ projb)
{
    __shared__ ushort smem[16896];
    gemm_body<0>(ctxb, wob, bo, projb, smem, blockIdx.x, blockIdx.y);
}

// ---------------- flash attention (S^T formulation) ----------------
// grid: 768 blocks decoded qt = bid/96, head = bid%96 so all 8 q-tiles of one
// head are ≡ same mod 8 -> same XCD -> K/V L2 reuse.
__global__ __launch_bounds__(256, 4) void attn(
    const ushort* __restrict__ Q, const ushort* __restrict__ Kc,
    const ushort* __restrict__ Vt, const float* __restrict__ mask,
    ushort* __restrict__ ctx)
{
    __shared__ ushort lK[64*64];
    __shared__ ushort lV[64*64];
    __shared__ ushort lP[4][32*72];    // also reused as 128x68 output tile
    __shared__ float  lmask[S_];

    const float SC = 0.125f * 1.44269504f;

    int bid = blockIdx.x;
    int qt = bid / (B_*NH_);           // 0..7
    int hl = bid % (B_*NH_);           // 0..95
    int h  = hl % NH_;
    int b  = hl / NH_;

    int tid  = threadIdx.x;
    int lane = tid & 63, w = tid >> 6;
    int fr = lane & 15, quad = lane >> 4;
    int quad4 = quad*4, sw = fr & 7;

    for (int i = tid; i < S_; i += 256)
        lmask[i] = (1.0f - mask[b*S_ + i]) * -14426.95f;

    short8 qf[2][2];
    #pragma unroll
    for (int nq=0;nq<2;nq++){
        const ushort* Qp = Q + (size_t)(b*S_ + qt*128 + w*32 + nq*16 + fr)*H_ + h*HD_ + quad*8;
        qf[nq][0] = *(const short8*)(Qp);
        qf[nq][1] = *(const short8*)(Qp + 32);
    }

    floatx4 O[4][2];   // [d-tile][q-tile] after PV swap
    #pragma unroll
    for (int dt=0;dt<4;dt++)
        #pragma unroll
        for (int qt2=0;qt2<2;qt2++)
            O[dt][qt2] = (floatx4){0.f,0.f,0.f,0.f};
    float rs0 = 0.f, rs1 = 0.f;

    int n0 = tid,       r0 = n0 >> 3, c0 = (n0 & 7) ^ (r0 & 7);
    int n1 = 256 + tid, r1 = n1 >> 3, c1 = (n1 & 7) ^ (r1 & 7);
    const ushort* pK0 = Kc + (size_t)(b*S_ + r0)*H_ + h*HD_ + c0*8;
    const ushort* pK1 = Kc + (size_t)(b*S_ + r1)*H_ + h*HD_ + c1*8;
    const ushort* pV0 = Vt + ((size_t)(b*NH_ + h)*HD_ + r0)*S_ + c0*8;
    const ushort* pV1 = Vt + ((size_t)(b*NH_ + h)*HD_ + r1)*S_ + c1*8;
    ushort* dK0 = &lK[n0*8]; ushort* dK1 = &lK[n1*8];
    ushort* dV0 = &lV[n0*8]; ushort* dV1 = &lV[n1*8];

    ushort* lPw = &lP[w][0];

    for (int kt = 0; kt < 16; kt++){
        __syncthreads();
        async16(pK0, dK0); async16(pK1, dK1);
        async16(pV0, dV0); async16(pV1, dV1);
        pK0 += (size_t)64*H_; pK1 += (size_t)64*H_;
        pV0 += 64; pV1 += 64;
        __syncthreads();

        float4 mk4[4];
        #pragma unroll
        for (int mk=0;mk<4;mk++)
            mk4[mk] = *(const float4*)&lmask[kt*64 + mk*16 + quad4];

        short8 kf[4][2];
        #pragma unroll
        for (int mk=0;mk<4;mk++){
            int row = mk*16 + fr;
            kf[mk][0] = *(const short8*)&lK[row*64 + ((quad     ^ sw)<<3)];
            kf[mk][1] = *(const short8*)&lK[row*64 + (((4+quad) ^ sw)<<3)];
        }
        floatx4 st[2][4];
        #pragma unroll
        for (int nq=0;nq<2;nq++)
            #pragma unroll
            for (int mk=0;mk<4;mk++){
                floatx4 a = (floatx4){0.f,0.f,0.f,0.f};
                a = MFMA16(kf[mk][0], qf[nq][0], a);
                a = MFMA16(kf[mk][1], qf[nq][1], a);
                st[nq][mk] = a;
            }

        #pragma unroll
        for (int nq=0;nq<2;nq++){
            #pragma unroll
            for (int mk=0;mk<4;mk++){
                floatx4 s = st[nq][mk];
                #pragma unroll
                for (int r=0;r<4;r++)
                    s[r] = __builtin_amdgcn_exp2f(s[r]*SC + mk4[mk][r]);
                if (nq == 0) rs0 += (s[0]+s[1]) + (s[2]+s[3]);
                else         rs1 += (s[0]+s[1]) + (s[2]+s[3]);
                unsigned lo = __builtin_amdgcn_perm(__float_as_uint(s[1]), __float_as_uint(s[0]), 0x07060302u);
                unsigned hi = __builtin_amdgcn_perm(__float_as_uint(s[3]), __float_as_uint(s[2]), 0x07060302u);
                uint2 pk; pk.x = lo; pk.y = hi;
                *(uint2*)&lPw[(nq*16 + fr)*72 + mk*16 + quad4] = pk;
            }
        }

        short8 vf[4][2];
        #pragma unroll
        for (int nt=0;nt<4;nt++){
            int row = nt*16 + fr;
            vf[nt][0] = *(const short8*)&lV[row*64 + ((quad     ^ sw)<<3)];
            vf[nt][1] = *(const short8*)&lV[row*64 + (((4+quad) ^ sw)<<3)];
        }
        short8 pf[2][2];
        #pragma unroll
        for (int mt=0;mt<2;mt++){
            pf[mt][0] = *(const short8*)&lPw[(mt*16+fr)*72 + quad*8];
            pf[mt][1] = *(const short8*)&lPw[(mt*16+fr)*72 + 32 + quad*8];
        }
        // swapped PV: O[d][q] — lane's q == fr == softmax-sum index
        #pragma unroll
        for (int dt=0;dt<4;dt++)
            #pragma unroll
            for (int qt2=0;qt2<2;qt2++){
                O[dt][qt2] = MFMA16(vf[dt][0], pf[qt2][0], O[dt][qt2]);
                O[dt][qt2] = MFMA16(vf[dt][1], pf[qt2][1], O[dt][qt2]);
            }
    }

    rs0 += __shfl_xor(rs0, 16); rs0 += __shfl_xor(rs0, 32);
    rs1 += __shfl_xor(rs1, 16); rs1 += __shfl_xor(rs1, 32);
    float i0 = 1.0f / rs0, i1 = 1.0f / rs1;

    // assemble [128 tok][64 d] tile (pitch 68) in lP space, then coalesced store
    ushort* lO = &lP[0][0];
    __syncthreads();
    #pragma unroll
    for (int dt=0;dt<4;dt++)
        #pragma unroll
        for (int qt2=0;qt2<2;qt2++){
            float iv = qt2 ? i1 : i0;
            ushort4 u;
            u.x = f2bf(O[dt][qt2][0] * iv);
            u.y = f2bf(O[dt][qt2][1] * iv);
            u.z = f2bf(O[dt][qt2][2] * iv);
            u.w = f2bf(O[dt][qt2][3] * iv);
            *(ushort4*)&lO[(w*32 + qt2*16 + fr)*68 + dt*16 + quad4] = u;
        }
    __syncthreads();
    int tokbase = b*S_ + qt*128;
    #pragma unroll
    for (int jj=0;jj<4;jj++){
        int idx = tid + 256*jj;            // 0..1023
        int q = idx >> 3, c = (idx & 7) * 8;
        short8 v = *(const short8*)&lO[q*68 + c];
        *(short8*)&ctx[(size_t)(tokbase + q)*H_ + h*HD_ + c] = v;
    }
}

// ---------------- residual + LayerNorm (bf16 proj in) ----------------
__global__ __launch_bounds__(256, 4) void resid_ln(
    const ushort* __restrict__ projb, const float* __restrict__ hs,
    const float* __restrict__ g, const float* __restrict__ be,
    float* __restrict__ out)
{
    int row = blockIdx.x;
    int tid = threadIdx.x;
    const ushort* p = projb + (size_t)row*H_;
    const float* x = hs   + (size_t)row*H_;
    float v[3]; float s = 0.f, s2 = 0.f;
    #pragma unroll
    for (int j=0;j<3;j++){
        float t = bf2f(p[tid + j*256]) + x[tid + j*256];
        v[j] = t; s += t; s2 += t*t;
    }
    #pragma unroll
    for (int off=1; off<64; off<<=1){
        s  += __shfl_xor(s,  off);
        s2 += __shfl_xor(s2, off);
    }
    __shared__ float rs[4], rs2[4];
    if ((tid & 63) == 0){ rs[tid>>6] = s; rs2[tid>>6] = s2; }
    __syncthreads();
    s  = rs[0]+rs[1]+rs[2]+rs[3];
    s2 = rs2[0]+rs2[1]+rs2[2]+rs2[3];
    float mu  = s * (1.f/H_);
    float var = s2*(1.f/H_) - mu*mu;
    float rinv = rsqrtf(var + 1e-5f);
    float* o = out + (size_t)row*H_;
    #pragma unroll
    for (int j=0;j<3;j++){
        int c = tid + j*256;
        o[c] = (v[j]-mu)*rinv*g[c] + be[c];
    }
}

extern "C" void kernel_launch(void* const* d_in, const int* in_sizes, int n_in,
                              void* d_out, int out_size, void* d_ws, size_t ws_size,
                              hipStream_t stream)
{
    (void)in_sizes; (void)n_in; (void)out_size; (void)ws_size;
    const float* hs   = (const float*)d_in[0];
    const float* ce   = (const float*)d_in[1];
    const float* mask = (const float*)d_in[2];
    const float* Wq   = (const float*)d_in[3];
    const float* bq   = (const float*)d_in[4];
    const float* Wk   = (const float*)d_in[5];
    const float* bk   = (const float*)d_in[6];
    const float* Wv   = (const float*)d_in[7];
    const float* bv   = (const float*)d_in[8];
    const float* Wo   = (const float*)d_in[9];
    const float* bo   = (const float*)d_in[10];
    const float* lg   = (const float*)d_in[11];
    const float* lb   = (const float*)d_in[12];
    float* out = (float*)d_out;

    char* ws = (char*)d_ws;
    const size_t SZ_ACT = (size_t)M_*H_*2;
    const size_t SZ_W   = (size_t)H_*H_*2;
    ushort* hsb  = (ushort*)(ws);
    ushort* ceb  = (ushort*)(ws + SZ_ACT);
    ushort* wqb  = (ushort*)(ws + 2*SZ_ACT);
    ushort* wkb  = (ushort*)(ws + 2*SZ_ACT + 1*SZ_W);
    ushort* wvb  = (ushort*)(ws + 2*SZ_ACT + 2*SZ_W);
    ushort* wob  = (ushort*)(ws + 2*SZ_ACT + 3*SZ_W);
    ushort* Qb   = (ushort*)(ws + 2*SZ_ACT + 4*SZ_W);
    ushort* Kb   = (ushort*)(ws + 3*SZ_ACT + 4*SZ_W);
    ushort* Vtb  = (ushort*)(ws + 4*SZ_ACT + 4*SZ_W);
    ushort* ctxb = (ushort*)(ws + 5*SZ_ACT + 4*SZ_W);
    ushort* projb = (ushort*)(ws);   // aliases hsb (dead after gemm_qkv)

    int ncvt = 2*(M_*H_/4) + 4*(H_*H_/4);
    cvt_all<<<dim3((ncvt+255)/256), dim3(256), 0, stream>>>(
        hs, ce, Wq, Wk, Wv, Wo, hsb, ceb, wqb, wkb, wvb, wob);

    gemm_qkv<<<dim3(M_/128, H_/128, 3), dim3(256), 0, stream>>>(
        hsb, ceb, wqb, wkb, wvb, bq, bk, bv, Qb, Kb, Vtb);

    attn<<<dim3(B_*NH_*8), dim3(256), 0, stream>>>(Qb, Kb, Vtb, mask, ctxb);

    gemm_o<<<dim3(M_/128, H_/128), dim3(256), 0, stream>>>(ctxb, wob, bo, projb);

    resid_ln<<<dim3(M_), dim3(256), 0, stream>>>(projb, hs, lg, lb, out);
}

// Round 5
// 230.539 us; speedup vs baseline: 1.1971x; 1.1971x over previous
//
#include <hip/hip_runtime.h>
#include <stdint.h>

#define B_ 8
#define S_ 1024
#define H_ 768
#define NH_ 12
#define HD_ 64
#define M_ (B_*S_)   // 8192 tokens

typedef __attribute__((ext_vector_type(8))) short short8;
typedef __attribute__((ext_vector_type(4))) float floatx4;

#define MFMA16(a,b,c) __builtin_amdgcn_mfma_f32_16x16x32_bf16((a),(b),(c),0,0,0)

__device__ __forceinline__ ushort f2bf(float x){
    union { float f; unsigned u; } v; v.f = x;
    unsigned r = (v.u + 0x7fffu + ((v.u >> 16) & 1u)) >> 16;
    return (ushort)r;
}
__device__ __forceinline__ float bf2f(ushort u){
    return __uint_as_float(((unsigned)u) << 16);
}

__device__ __forceinline__ void async16(const ushort* g, ushort* l){
    __builtin_amdgcn_global_load_lds(
        (const __attribute__((address_space(1))) unsigned int*)g,
        (__attribute__((address_space(3))) unsigned int*)l, 16, 0, 0);
}

// ---------------- fused f32 -> bf16 cast for all 6 tensors ----------------
__global__ __launch_bounds__(256, 8) void cvt_all(
    const float* __restrict__ hs, const float* __restrict__ ce,
    const float* __restrict__ wq, const float* __restrict__ wk,
    const float* __restrict__ wv, const float* __restrict__ wo,
    ushort* __restrict__ hsb, ushort* __restrict__ ceb,
    ushort* __restrict__ wqb, ushort* __restrict__ wkb,
    ushort* __restrict__ wvb, ushort* __restrict__ wob)
{
    const int NA = M_*H_/4;
    const int NW = H_*H_/4;
    int i = blockIdx.x*256 + threadIdx.x;
    if (i >= 2*NA + 4*NW) return;
    const float* s; ushort* d; int off;
    if (i < NA)            { s = hs; d = hsb; off = i; }
    else if (i < 2*NA)     { s = ce; d = ceb; off = i - NA; }
    else {
        int j = i - 2*NA;
        int wsel = j / NW;
        off = j - wsel*NW;
        s = (wsel==0) ? wq : (wsel==1) ? wk : (wsel==2) ? wv : wo;
        d = (wsel==0) ? wqb : (wsel==1) ? wkb : (wsel==2) ? wvb : wob;
    }
    float4 f = ((const float4*)s)[off];
    ushort4 u;
    u.x = f2bf(f.x); u.y = f2bf(f.y); u.z = f2bf(f.z); u.w = f2bf(f.w);
    ((ushort4*)d)[off] = u;
}

// ---------------- shared GEMM body: C[M,N] = A[M,K] @ B[N,K]^T + bias ------
// BK=64, XOR-swizzled 128B-pitch LDS rows.
// MODE 0: swapped-operand MFMA (D[n][m]); bf16 out [M,768] via LDS-assembled
//         coalesced b128 stores.
// MODE 1: Vt[(b*12+h)*64+d][1024] via LDS-assembled coalesced stores.
// NOTE: launch_bounds must stay at 3 waves/EU (>=170 reg cap). At 4 the
// unified VGPR+AGPR cap is 128 -> K-loop spills to scratch -> 120MB of HBM
// spill traffic (measured round 4: WRITE 42->160MB, dur +57%).
template<int MODE>
__device__ __forceinline__ void gemm_body(
    const ushort* __restrict__ A, const ushort* __restrict__ Bw,
    const float* __restrict__ bias, ushort* __restrict__ obf,
    ushort* smem, int bx, int by)
{
    ushort* lA = smem;
    ushort* lB = smem + 8192;
    const int K = H_;
    int tid  = threadIdx.x;
    int lane = tid & 63, wave = tid >> 6;
    int m0 = bx * 128, n0 = by * 128;
    int wm = (wave >> 1) * 64, wn = (wave & 1) * 64;
    int fr = lane & 15, quad = lane >> 4, quad4 = quad*4;

    floatx4 acc[4][4];
    #pragma unroll
    for (int mt=0;mt<4;mt++)
        #pragma unroll
        for (int nt=0;nt<4;nt++)
            acc[mt][nt] = (floatx4){0.f,0.f,0.f,0.f};

    int row0 = tid >> 3;
    int csw  = ((tid & 7) ^ (row0 & 7)) * 8;
    const ushort* Ap[4]; const ushort* Bp[4];
    ushort* ldA_[4]; ushort* ldB_[4];
    #pragma unroll
    for (int j=0;j<4;j++){
        int row = row0 + 32*j;
        Ap[j] = A  + (size_t)(m0 + row) * K + csw;
        Bp[j] = Bw + (size_t)(n0 + row) * K + csw;
        ldA_[j] = lA + (tid + 256*j)*8;
        ldB_[j] = lB + (tid + 256*j)*8;
    }

    for (int k0 = 0; k0 < K; k0 += 64){
        #pragma unroll
        for (int j=0;j<4;j++) async16(Ap[j] + k0, ldA_[j]);
        #pragma unroll
        for (int j=0;j<4;j++) async16(Bp[j] + k0, ldB_[j]);
        __syncthreads();
        #pragma unroll
        for (int kk=0; kk<2; kk++){
            short8 af[4], bfr[4];
            #pragma unroll
            for (int t=0;t<4;t++){
                int ra = wm + t*16 + fr;
                int rb = wn + t*16 + fr;
                af[t]  = *(const short8*)&lA[ra*64 + (((kk*4+quad) ^ (ra&7))<<3)];
                bfr[t] = *(const short8*)&lB[rb*64 + (((kk*4+quad) ^ (rb&7))<<3)];
            }
            if (MODE == 0){
                // swapped: D[n][m] — lane holds 4 consecutive n for one token m
                #pragma unroll
                for (int mt=0;mt<4;mt++)
                    #pragma unroll
                    for (int nt=0;nt<4;nt++)
                        acc[mt][nt] = MFMA16(bfr[nt], af[mt], acc[mt][nt]);
            } else {
                #pragma unroll
                for (int mt=0;mt<4;mt++)
                    #pragma unroll
                    for (int nt=0;nt<4;nt++)
                        acc[mt][nt] = MFMA16(af[mt], bfr[nt], acc[mt][nt]);
            }
        }
        __syncthreads();
    }

    if (MODE == 0){
        // bias along n, vectorized: lane's 4 accs are consecutive n
        float4 bias4[4];
        #pragma unroll
        for (int nt=0;nt<4;nt++)
            bias4[nt] = *(const float4*)&bias[n0 + wn + nt*16 + quad4];
        // assemble [m][n] tile, pitch 132
        #pragma unroll
        for (int mt=0;mt<4;mt++){
            int m = wm + mt*16 + fr;
            #pragma unroll
            for (int nt=0;nt<4;nt++){
                ushort4 u;
                u.x = f2bf(acc[mt][nt][0] + bias4[nt].x);
                u.y = f2bf(acc[mt][nt][1] + bias4[nt].y);
                u.z = f2bf(acc[mt][nt][2] + bias4[nt].z);
                u.w = f2bf(acc[mt][nt][3] + bias4[nt].w);
                *(ushort4*)&smem[m*132 + wn + nt*16 + quad4] = u;
            }
        }
        __syncthreads();
        #pragma unroll
        for (int jj=0;jj<8;jj++){
            int idx = tid + 256*jj;          // 0..2047
            int m = idx >> 4, c = (idx & 15) * 8;
            short8 v = *(const short8*)&smem[m*132 + c];
            *(short8*)&obf[(size_t)(m0 + m)*H_ + n0 + c] = v;
        }
    } else {
        float bv_[4];
        #pragma unroll
        for (int nt=0;nt<4;nt++) bv_[nt] = bias[n0 + wn + nt*16 + fr];
        // Vt: assemble per head-half [64 d][pitch 136 q], store coalesced
        int bb = m0 >> 10, q0 = m0 & 1023;
        #pragma unroll
        for (int nh=0; nh<2; nh++){
            __syncthreads();
            if ((wave & 1) == nh){
                #pragma unroll
                for (int mt=0;mt<4;mt++){
                    int ql = wm + mt*16 + quad4;
                    #pragma unroll
                    for (int nt=0;nt<4;nt++){
                        int dl = nt*16 + fr;
                        ushort4 u;
                        u.x = f2bf(acc[mt][nt][0] + bv_[nt]);
                        u.y = f2bf(acc[mt][nt][1] + bv_[nt]);
                        u.z = f2bf(acc[mt][nt][2] + bv_[nt]);
                        u.w = f2bf(acc[mt][nt][3] + bv_[nt]);
                        *(ushort4*)&smem[dl*136 + ql] = u;
                    }
                }
            }
            __syncthreads();
            int head = by*2 + nh;
            #pragma unroll
            for (int jj=0;jj<4;jj++){
                int mI = tid + 256*jj;
                int d  = mI >> 4;
                int qc = (mI & 15) * 8;
                short8 v = *(const short8*)&smem[d*136 + qc];
                *(short8*)&obf[((size_t)((bb*NH_ + head)*HD_ + d))*S_ + q0 + qc] = v;
            }
        }
    }
}

// fused Q/K/V projection: grid (64, 6, 3)
__global__ __launch_bounds__(256, 3) void gemm_qkv(
    const ushort* __restrict__ hsb, const ushort* __restrict__ ceb,
    const ushort* __restrict__ wqb, const ushort* __restrict__ wkb,
    const ushort* __restrict__ wvb,
    const float* __restrict__ bq, const float* __restrict__ bk,
    const float* __restrict__ bv,
    ushort* __restrict__ Qb, ushort* __restrict__ Kb, ushort* __restrict__ Vtb)
{
    __shared__ ushort smem[16896];
    int z = blockIdx.z;
    if (z == 2)
        gemm_body<1>(ceb, wvb, bv, Vtb, smem, blockIdx.x, blockIdx.y);
    else
        gemm_body<0>(z ? ceb : hsb, z ? wkb : wqb, z ? bk : bq,
                     z ? Kb : Qb, smem, blockIdx.x, blockIdx.y);
}

// O-projection (bf16 out): grid (64, 6)
__global__ __launch_bounds__(256, 3) void gemm_o(
    const ushort* __restrict__ ctxb, const ushort* __restrict__ wob,
    const float* __restrict__ bo, ushort* __restrict__ projb)
{
    __shared__ ushort smem[16896];
    gemm_body<0>(ctxb, wob, bo, projb, smem, blockIdx.x, blockIdx.y);
}

// ---------------- flash attention (S^T formulation) ----------------
// grid: 768 blocks decoded qt = bid/96, head = bid%96 so all 8 q-tiles of one
// head are ≡ same mod 8 -> same XCD -> K/V L2 reuse.
__global__ __launch_bounds__(256, 3) void attn(
    const ushort* __restrict__ Q, const ushort* __restrict__ Kc,
    const ushort* __restrict__ Vt, const float* __restrict__ mask,
    ushort* __restrict__ ctx)
{
    __shared__ ushort lK[64*64];
    __shared__ ushort lV[64*64];
    __shared__ ushort lP[4][32*72];    // also reused as 128x68 output tile
    __shared__ float  lmask[S_];

    const float SC = 0.125f * 1.44269504f;

    int bid = blockIdx.x;
    int qt = bid / (B_*NH_);           // 0..7
    int hl = bid % (B_*NH_);           // 0..95
    int h  = hl % NH_;
    int b  = hl / NH_;

    int tid  = threadIdx.x;
    int lane = tid & 63, w = tid >> 6;
    int fr = lane & 15, quad = lane >> 4;
    int quad4 = quad*4, sw = fr & 7;

    for (int i = tid; i < S_; i += 256)
        lmask[i] = (1.0f - mask[b*S_ + i]) * -14426.95f;

    short8 qf[2][2];
    #pragma unroll
    for (int nq=0;nq<2;nq++){
        const ushort* Qp = Q + (size_t)(b*S_ + qt*128 + w*32 + nq*16 + fr)*H_ + h*HD_ + quad*8;
        qf[nq][0] = *(const short8*)(Qp);
        qf[nq][1] = *(const short8*)(Qp + 32);
    }

    floatx4 O[4][2];   // [d-tile][q-tile] after PV swap
    #pragma unroll
    for (int dt=0;dt<4;dt++)
        #pragma unroll
        for (int qt2=0;qt2<2;qt2++)
            O[dt][qt2] = (floatx4){0.f,0.f,0.f,0.f};
    float rs0 = 0.f, rs1 = 0.f;

    int n0 = tid,       r0 = n0 >> 3, c0 = (n0 & 7) ^ (r0 & 7);
    int n1 = 256 + tid, r1 = n1 >> 3, c1 = (n1 & 7) ^ (r1 & 7);
    const ushort* pK0 = Kc + (size_t)(b*S_ + r0)*H_ + h*HD_ + c0*8;
    const ushort* pK1 = Kc + (size_t)(b*S_ + r1)*H_ + h*HD_ + c1*8;
    const ushort* pV0 = Vt + ((size_t)(b*NH_ + h)*HD_ + r0)*S_ + c0*8;
    const ushort* pV1 = Vt + ((size_t)(b*NH_ + h)*HD_ + r1)*S_ + c1*8;
    ushort* dK0 = &lK[n0*8]; ushort* dK1 = &lK[n1*8];
    ushort* dV0 = &lV[n0*8]; ushort* dV1 = &lV[n1*8];

    ushort* lPw = &lP[w][0];

    for (int kt = 0; kt < 16; kt++){
        __syncthreads();
        async16(pK0, dK0); async16(pK1, dK1);
        async16(pV0, dV0); async16(pV1, dV1);
        pK0 += (size_t)64*H_; pK1 += (size_t)64*H_;
        pV0 += 64; pV1 += 64;
        __syncthreads();

        float4 mk4[4];
        #pragma unroll
        for (int mk=0;mk<4;mk++)
            mk4[mk] = *(const float4*)&lmask[kt*64 + mk*16 + quad4];

        short8 kf[4][2];
        #pragma unroll
        for (int mk=0;mk<4;mk++){
            int row = mk*16 + fr;
            kf[mk][0] = *(const short8*)&lK[row*64 + ((quad     ^ sw)<<3)];
            kf[mk][1] = *(const short8*)&lK[row*64 + (((4+quad) ^ sw)<<3)];
        }
        floatx4 st[2][4];
        #pragma unroll
        for (int nq=0;nq<2;nq++)
            #pragma unroll
            for (int mk=0;mk<4;mk++){
                floatx4 a = (floatx4){0.f,0.f,0.f,0.f};
                a = MFMA16(kf[mk][0], qf[nq][0], a);
                a = MFMA16(kf[mk][1], qf[nq][1], a);
                st[nq][mk] = a;
            }

        #pragma unroll
        for (int nq=0;nq<2;nq++){
            #pragma unroll
            for (int mk=0;mk<4;mk++){
                floatx4 s = st[nq][mk];
                #pragma unroll
                for (int r=0;r<4;r++)
                    s[r] = __builtin_amdgcn_exp2f(s[r]*SC + mk4[mk][r]);
                if (nq == 0) rs0 += (s[0]+s[1]) + (s[2]+s[3]);
                else         rs1 += (s[0]+s[1]) + (s[2]+s[3]);
                unsigned lo = __builtin_amdgcn_perm(__float_as_uint(s[1]), __float_as_uint(s[0]), 0x07060302u);
                unsigned hi = __builtin_amdgcn_perm(__float_as_uint(s[3]), __float_as_uint(s[2]), 0x07060302u);
                uint2 pk; pk.x = lo; pk.y = hi;
                *(uint2*)&lPw[(nq*16 + fr)*72 + mk*16 + quad4] = pk;
            }
        }

        short8 vf[4][2];
        #pragma unroll
        for (int nt=0;nt<4;nt++){
            int row = nt*16 + fr;
            vf[nt][0] = *(const short8*)&lV[row*64 + ((quad     ^ sw)<<3)];
            vf[nt][1] = *(const short8*)&lV[row*64 + (((4+quad) ^ sw)<<3)];
        }
        short8 pf[2][2];
        #pragma unroll
        for (int mt=0;mt<2;mt++){
            pf[mt][0] = *(const short8*)&lPw[(mt*16+fr)*72 + quad*8];
            pf[mt][1] = *(const short8*)&lPw[(mt*16+fr)*72 + 32 + quad*8];
        }
        // swapped PV: O[d][q] — lane's q == fr == softmax-sum index
        #pragma unroll
        for (int dt=0;dt<4;dt++)
            #pragma unroll
            for (int qt2=0;qt2<2;qt2++){
                O[dt][qt2] = MFMA16(vf[dt][0], pf[qt2][0], O[dt][qt2]);
                O[dt][qt2] = MFMA16(vf[dt][1], pf[qt2][1], O[dt][qt2]);
            }
    }

    rs0 += __shfl_xor(rs0, 16); rs0 += __shfl_xor(rs0, 32);
    rs1 += __shfl_xor(rs1, 16); rs1 += __shfl_xor(rs1, 32);
    float i0 = 1.0f / rs0, i1 = 1.0f / rs1;

    // assemble [128 tok][64 d] tile (pitch 68) in lP space, then coalesced store
    ushort* lO = &lP[0][0];
    __syncthreads();
    #pragma unroll
    for (int dt=0;dt<4;dt++)
        #pragma unroll
        for (int qt2=0;qt2<2;qt2++){
            float iv = qt2 ? i1 : i0;
            ushort4 u;
            u.x = f2bf(O[dt][qt2][0] * iv);
            u.y = f2bf(O[dt][qt2][1] * iv);
            u.z = f2bf(O[dt][qt2][2] * iv);
            u.w = f2bf(O[dt][qt2][3] * iv);
            *(ushort4*)&lO[(w*32 + qt2*16 + fr)*68 + dt*16 + quad4] = u;
        }
    __syncthreads();
    int tokbase = b*S_ + qt*128;
    #pragma unroll
    for (int jj=0;jj<4;jj++){
        int idx = tid + 256*jj;            // 0..1023
        int q = idx >> 3, c = (idx & 7) * 8;
        short8 v = *(const short8*)&lO[q*68 + c];
        *(short8*)&ctx[(size_t)(tokbase + q)*H_ + h*HD_ + c] = v;
    }
}

// ---------------- residual + LayerNorm (bf16 proj in) ----------------
__global__ __launch_bounds__(256, 4) void resid_ln(
    const ushort* __restrict__ projb, const float* __restrict__ hs,
    const float* __restrict__ g, const float* __restrict__ be,
    float* __restrict__ out)
{
    int row = blockIdx.x;
    int tid = threadIdx.x;
    const ushort* p = projb + (size_t)row*H_;
    const float* x = hs   + (size_t)row*H_;
    float v[3]; float s = 0.f, s2 = 0.f;
    #pragma unroll
    for (int j=0;j<3;j++){
        float t = bf2f(p[tid + j*256]) + x[tid + j*256];
        v[j] = t; s += t; s2 += t*t;
    }
    #pragma unroll
    for (int off=1; off<64; off<<=1){
        s  += __shfl_xor(s,  off);
        s2 += __shfl_xor(s2, off);
    }
    __shared__ float rs[4], rs2[4];
    if ((tid & 63) == 0){ rs[tid>>6] = s; rs2[tid>>6] = s2; }
    __syncthreads();
    s  = rs[0]+rs[1]+rs[2]+rs[3];
    s2 = rs2[0]+rs2[1]+rs2[2]+rs2[3];
    float mu  = s * (1.f/H_);
    float var = s2*(1.f/H_) - mu*mu;
    float rinv = rsqrtf(var + 1e-5f);
    float* o = out + (size_t)row*H_;
    #pragma unroll
    for (int j=0;j<3;j++){
        int c = tid + j*256;
        o[c] = (v[j]-mu)*rinv*g[c] + be[c];
    }
}

extern "C" void kernel_launch(void* const* d_in, const int* in_sizes, int n_in,
                              void* d_out, int out_size, void* d_ws, size_t ws_size,
                              hipStream_t stream)
{
    (void)in_sizes; (void)n_in; (void)out_size; (void)ws_size;
    const float* hs   = (const float*)d_in[0];
    const float* ce   = (const float*)d_in[1];
    const float* mask = (const float*)d_in[2];
    const float* Wq   = (const float*)d_in[3];
    const float* bq   = (const float*)d_in[4];
    const float* Wk   = (const float*)d_in[5];
    const float* bk   = (const float*)d_in[6];
    const float* Wv   = (const float*)d_in[7];
    const float* bv   = (const float*)d_in[8];
    const float* Wo   = (const float*)d_in[9];
    const float* bo   = (const float*)d_in[10];
    const float* lg   = (const float*)d_in[11];
    const float* lb   = (const float*)d_in[12];
    float* out = (float*)d_out;

    char* ws = (char*)d_ws;
    const size_t SZ_ACT = (size_t)M_*H_*2;
    const size_t SZ_W   = (size_t)H_*H_*2;
    ushort* hsb  = (ushort*)(ws);
    ushort* ceb  = (ushort*)(ws + SZ_ACT);
    ushort* wqb  = (ushort*)(ws + 2*SZ_ACT);
    ushort* wkb  = (ushort*)(ws + 2*SZ_ACT + 1*SZ_W);
    ushort* wvb  = (ushort*)(ws + 2*SZ_ACT + 2*SZ_W);
    ushort* wob  = (ushort*)(ws + 2*SZ_ACT + 3*SZ_W);
    ushort* Qb   = (ushort*)(ws + 2*SZ_ACT + 4*SZ_W);
    ushort* Kb   = (ushort*)(ws + 3*SZ_ACT + 4*SZ_W);
    ushort* Vtb  = (ushort*)(ws + 4*SZ_ACT + 4*SZ_W);
    ushort* ctxb = (ushort*)(ws + 5*SZ_ACT + 4*SZ_W);
    ushort* projb = (ushort*)(ws);   // aliases hsb (dead after gemm_qkv)

    int ncvt = 2*(M_*H_/4) + 4*(H_*H_/4);
    cvt_all<<<dim3((ncvt+255)/256), dim3(256), 0, stream>>>(
        hs, ce, Wq, Wk, Wv, Wo, hsb, ceb, wqb, wkb, wvb, wob);

    gemm_qkv<<<dim3(M_/128, H_/128, 3), dim3(256), 0, stream>>>(
        hsb, ceb, wqb, wkb, wvb, bq, bk, bv, Qb, Kb, Vtb);

    attn<<<dim3(B_*NH_*8), dim3(256), 0, stream>>>(Qb, Kb, Vtb, mask, ctxb);

    gemm_o<<<dim3(M_/128, H_/128), dim3(256), 0, stream>>>(ctxb, wob, bo, projb);

    resid_ln<<<dim3(M_), dim3(256), 0, stream>>>(projb, hs, lg, lb, out);
}